// Round 10
// baseline (453.065 us; speedup 1.0000x reference)
//
#include <hip/hip_runtime.h>

// Problem constants (fixed by reference)
#define NAG   16
#define OBSD  256
#define ACTD  32
#define SCF   16
#define H1D   128
#define H2D   64
#define BT    1024          // B*T
#define NTOK  16384         // BT*NAG
#define NEVAL 18

typedef float f4 __attribute__((ext_vector_type(4)));

// ---- LDS float-offset map ----
// persistent: W2s [0,8192) 128x64
// per-team:   Hs  [8192 + team*4096) 32x128 swizzled
//             H2s [16384 + team*2048) 32x64 swizzled
// prologue overlays: OBS [8192,16384) 32x256 ; BS/hobs [16384,20480) 32x128
#define W2S_OFF  0
#define HS_OFF   8192
#define H2S_OFF  16384
#define OBS_OFF  8192
#define BS_OFF   16384
#define LDS_FLOATS 20480     // 81920 B -> exactly 2 blocks/CU (160 KiB pool)

// row-dependent XOR swizzles (float-unit offsets, 4-aligned -> b128-safe)
#define X1(r) (((r) & 7) << 2)   // Hs  (row stride 128)
#define X2(r) (((r) & 7) << 3)   // H2s (row stride 64)

// ---------------------------------------------------------------------------
// 512 threads = 2 teams x 256. Block = 32 tokens, grid 512.
// Prologue (all 512): hobs = obs @ W1[0:256,:] + b1 -> LDS handoff -> regs.
// Team eval loop (9 iters): team0 {with, cf 0..7}, team1 {zero, cf 8..15}.
//   GEMM1: A (acts/cf) + B (W1a) from global/L1; h1 -> team Hs.
//   GEMM2: split-k over W2s(shared LDS); partials combined in team H2s.
//   GEMM3: W3 from L1; accumulate pw/pq in regs.
// Epilogue: team1 publishes pq via LDS; team0 computes KL -> out.
// ---------------------------------------------------------------------------
__global__ __launch_bounds__(512, 4) void k_fused(
    const float* __restrict__ obs, const float* __restrict__ actions,
    const float* __restrict__ cf, const float* __restrict__ W1,
    const float* __restrict__ b1, const float* __restrict__ W2,
    const float* __restrict__ b2v, const float* __restrict__ W3,
    const float* __restrict__ b3v, float* __restrict__ out)
{
    __shared__ float lds[LDS_FLOATS];

    const int tid  = threadIdx.x;
    const int team = tid >> 8;
    const int ttid = tid & 255;
    const int g0   = blockIdx.x * 32;

    // prologue mapping: 2 tok x 4 col over 512 threads
    const int rp = tid >> 5;            // 0..15 -> rows rp*2+{0,1}
    const int cp = tid & 31;            // cols cp*4
    // team mappings (on ttid, identical to validated R6 kernel)
    const int rb1 = ttid >> 5, cb1 = ttid & 31;       // GEMM1: 4 tok x 4 col
    const int kh  = ttid >> 7;                        // GEMM2 k-half
    const int rg  = (ttid >> 4) & 7, cg = ttid & 15;  // GEMM2: 4 tok x 4 col
    const int r3  = ttid >> 3, cb3 = ttid & 7;        // GEMM3: 1 tok x 4 col

    // ---- stage W2 (shared, 2048 f4) + obs tile (2048 f4) ----
    #pragma unroll
    for (int j = 0; j < 4; ++j) {
        int idx = tid + j * 512;
        *(f4*)(lds + W2S_OFF + idx * 4) = *(const f4*)(W2 + idx * 4);
        *(f4*)(lds + OBS_OFF + idx * 4) = *(const f4*)(obs + g0 * OBSD + idx * 4);
    }
    __syncthreads();

    // ---- prologue obs-GEMM: K=256 in 8 staged k-tiles ----
    f4 pacc[2] = {{0.f,0.f,0.f,0.f},{0.f,0.f,0.f,0.f}};
    for (int kt = 0; kt < OBSD; kt += 32) {
        // stage W1 rows kt..kt+31 (1024 f4)
        #pragma unroll
        for (int j = 0; j < 2; ++j) {
            int idx = tid + j * 512;
            *(f4*)(lds + BS_OFF + idx * 4) = *(const f4*)(W1 + kt * H1D + idx * 4);
        }
        __syncthreads();
        #pragma unroll
        for (int k0 = 0; k0 < 32; k0 += 4) {
            f4 a0 = *(const f4*)(lds + OBS_OFF + (rp * 2 + 0) * OBSD + kt + k0);
            f4 a1 = *(const f4*)(lds + OBS_OFF + (rp * 2 + 1) * OBSD + kt + k0);
            #pragma unroll
            for (int kk = 0; kk < 4; ++kk) {
                f4 b = *(const f4*)(lds + BS_OFF + (k0 + kk) * H1D + cp * 4);
                pacc[0] += b * a0[kk];
                pacc[1] += b * a1[kk];
            }
        }
        __syncthreads();
    }
    // write hobs (+b1) to handoff buffer (BS region dead)
    {
        f4 bias = *(const f4*)(b1 + cp * 4);
        *(f4*)(lds + BS_OFF + (rp * 2 + 0) * H1D + cp * 4) = pacc[0] + bias;
        *(f4*)(lds + BS_OFF + (rp * 2 + 1) * H1D + cp * 4) = pacc[1] + bias;
    }
    __syncthreads();
    // each team-thread reads its 4x4 hobs fragment
    f4 hobs[4];
    #pragma unroll
    for (int i = 0; i < 4; ++i)
        hobs[i] = *(const f4*)(lds + BS_OFF + (rb1 * 4 + i) * H1D + cb1 * 4);
    __syncthreads();   // handoff region becomes H2s

    const float* W1a = W1 + OBSD * H1D;
    f4 bias2 = *(const f4*)(b2v + cg * 4);
    f4 bias3 = *(const f4*)(b3v + cb3 * 4);

    // eval-invariant GEMM1-A addressing (validated in R6)
    const int row0 = rb1 * 4;
    const float* act_src = actions + (g0 + row0) * ACTD;
    const float* cf_base = cf + (row0 & 15) * (SCF * BT * ACTD)
                              + ((g0 >> 4) + (row0 >> 4)) * ACTD;

    const int hsT  = HS_OFF  + team * 4096;
    const int h2sT = H2S_OFF + team * 2048;

    f4 pw = {0.f, 0.f, 0.f, 0.f};
    f4 pq = {0.f, 0.f, 0.f, 0.f};

    // ================= team eval loop: 9 evals each =================
    for (int ee = 0; ee < 9; ++ee) {
        const bool zeroEval = (team == 1) && (ee == 0);
        const bool withEval = (team == 0) && (ee == 0);

        // --- GEMM1: h1 = relu(hobs + act @ W1a); A,B via global/L1 ---
        f4 hv[4];
        if (!zeroEval) {
            const float* asrc;
            int astr;
            if (withEval) { asrc = act_src; astr = ACTD; }
            else {
                int s = ee - 1 + team * 8;
                asrc = cf_base + s * (BT * ACTD);
                astr = SCF * BT * ACTD;
            }
            f4 a1c[4] = {{0.f,0.f,0.f,0.f},{0.f,0.f,0.f,0.f},
                         {0.f,0.f,0.f,0.f},{0.f,0.f,0.f,0.f}};
            #pragma unroll
            for (int k0 = 0; k0 < ACTD; k0 += 4) {
                f4 a[4];
                #pragma unroll
                for (int i = 0; i < 4; ++i)
                    a[i] = *(const f4*)(asrc + i * astr + k0);
                #pragma unroll
                for (int kk = 0; kk < 4; ++kk) {
                    f4 b = *(const f4*)(W1a + (k0 + kk) * H1D + cb1 * 4);
                    #pragma unroll
                    for (int i = 0; i < 4; ++i)
                        a1c[i] += b * a[i][kk];
                }
            }
            #pragma unroll
            for (int i = 0; i < 4; ++i)
                #pragma unroll
                for (int j = 0; j < 4; ++j)
                    hv[i][j] = fmaxf(hobs[i][j] + a1c[i][j], 0.f);
        } else {
            #pragma unroll
            for (int i = 0; i < 4; ++i)
                #pragma unroll
                for (int j = 0; j < 4; ++j)
                    hv[i][j] = fmaxf(hobs[i][j], 0.f);
        }
        #pragma unroll
        for (int i = 0; i < 4; ++i) {
            int r = rb1 * 4 + i;
            *(f4*)(lds + hsT + r * H1D + ((cb1 * 4) ^ X1(r))) = hv[i];
        }
        __syncthreads();  // B_a: team Hs visible

        // --- GEMM2 split-k on shared W2s ---
        f4 acc2[4] = {{0.f,0.f,0.f,0.f},{0.f,0.f,0.f,0.f},
                      {0.f,0.f,0.f,0.f},{0.f,0.f,0.f,0.f}};
        {
            const int kb = kh * 64;
            #pragma unroll 8
            for (int k0 = 0; k0 < 64; k0 += 4) {
                f4 a[4];
                #pragma unroll
                for (int i = 0; i < 4; ++i) {
                    int r = rg * 4 + i;
                    a[i] = *(const f4*)(lds + hsT + r * H1D + ((kb + k0) ^ X1(r)));
                }
                #pragma unroll
                for (int kk = 0; kk < 4; ++kk) {
                    f4 b = *(const f4*)(lds + W2S_OFF + (kb + k0 + kk) * H2D + cg * 4);
                    #pragma unroll
                    for (int i = 0; i < 4; ++i)
                        acc2[i] += b * a[i][kk];
                }
            }
        }
        if (kh) {
            #pragma unroll
            for (int i = 0; i < 4; ++i) {
                int r = rg * 4 + i;
                *(f4*)(lds + h2sT + r * H2D + ((cg * 4) ^ X2(r))) = acc2[i];
            }
        }
        __syncthreads();  // B_b: partials visible
        if (!kh) {
            #pragma unroll
            for (int i = 0; i < 4; ++i) {
                int r = rg * 4 + i;
                float* p = lds + h2sT + r * H2D + ((cg * 4) ^ X2(r));
                f4 part = *(const f4*)p;
                f4 v;
                #pragma unroll
                for (int j = 0; j < 4; ++j)
                    v[j] = fmaxf(acc2[i][j] + part[j] + bias2[j], 0.f);
                *(f4*)p = v;
            }
        }
        __syncthreads();  // B_c: team H2s final

        // --- GEMM3: p = h2 @ W3 + b3 (W3 via L1) ---
        {
            f4 a3 = {0.f, 0.f, 0.f, 0.f};
            #pragma unroll 8
            for (int k0 = 0; k0 < H2D; k0 += 4) {
                f4 a = *(const f4*)(lds + h2sT + r3 * H2D + (k0 ^ X2(r3)));
                #pragma unroll
                for (int kk = 0; kk < 4; ++kk) {
                    f4 b = *(const f4*)(W3 + (k0 + kk) * ACTD + cb3 * 4);
                    a3 += b * a[kk];
                }
            }
            a3 += bias3;
            if (withEval) pw = a3;
            else {
                pq += a3;   // includes team1's zero eval
            }
        }
        __syncthreads();  // B_d: GEMM3 reads done before next eval's writes
    }

    // ================= combine + KL (team0) =================
    if (team) {
        // publish team1 pq into team1's dead Hs region
        *(f4*)(lds + HS_OFF + 4096 + r3 * 32 + cb3 * 4) = pq;
    }
    __syncthreads();
    if (!team) {
        f4 pq1 = *(const f4*)(lds + HS_OFF + 4096 + r3 * 32 + cb3 * 4);
        const float inv17 = 1.0f / 17.0f;
        f4 qv;
        #pragma unroll
        for (int j = 0; j < 4; ++j) qv[j] = (pq[j] + pq1[j]) * inv17;

        float mw = fmaxf(fmaxf(pw[0], pw[1]), fmaxf(pw[2], pw[3]));
        float mq = fmaxf(fmaxf(qv[0], qv[1]), fmaxf(qv[2], qv[3]));
        #pragma unroll
        for (int m = 1; m < 8; m <<= 1) {
            mw = fmaxf(mw, __shfl_xor(mw, m));
            mq = fmaxf(mq, __shfl_xor(mq, m));
        }
        float sw = 0.f, sq = 0.f;
        #pragma unroll
        for (int j = 0; j < 4; ++j) {
            sw += expf(pw[j] - mw);
            sq += expf(qv[j] - mq);
        }
        #pragma unroll
        for (int m = 1; m < 8; m <<= 1) {
            sw += __shfl_xor(sw, m);
            sq += __shfl_xor(sq, m);
        }
        const float lsw = logf(sw), lsq = logf(sq);
        float kl = 0.f;
        #pragma unroll
        for (int j = 0; j < 4; ++j) {
            float lq = qv[j] - mq - lsq;
            float lp = pw[j] - mw - lsw;
            kl += expf(lq) * (lq - lp);
        }
        #pragma unroll
        for (int m = 1; m < 8; m <<= 1) kl += __shfl_xor(kl, m);

        if (cb3 == 0) out[g0 + r3] = kl * (1.0f / 32.0f);
    }
}

// ---------------------------------------------------------------------------
extern "C" void kernel_launch(void* const* d_in, const int* in_sizes, int n_in,
                              void* d_out, int out_size, void* d_ws, size_t ws_size,
                              hipStream_t stream)
{
    const float* obs     = (const float*)d_in[0];
    const float* actions = (const float*)d_in[1];
    const float* cf      = (const float*)d_in[2];
    const float* W1      = (const float*)d_in[3];
    const float* b1      = (const float*)d_in[4];
    const float* W2      = (const float*)d_in[5];
    const float* b2      = (const float*)d_in[6];
    const float* W3      = (const float*)d_in[7];
    const float* b3      = (const float*)d_in[8];
    float* outp = (float*)d_out;

    k_fused<<<NTOK / 32, 512, 0, stream>>>(obs, actions, cf, W1, b1, W2,
                                           b2, W3, b3, outp);
}

// Round 12
// 440.624 us; speedup vs baseline: 1.0282x; 1.0282x over previous
//
#include <hip/hip_runtime.h>

// Problem constants (fixed by reference)
#define NAG   16
#define OBSD  256
#define ACTD  32
#define SCF   16
#define H1D   128
#define H2D   64
#define BT    1024          // B*T
#define NTOK  16384         // BT*NAG
#define NEVAL 18

typedef float f4 __attribute__((ext_vector_type(4)));

// ---- LDS float-offset map ----
// persistent: W2s [0,8192) 128x64
// per-team:   Hs  [8192 + team*4096) 32x128 swizzled
//             H2s [16384 + team*2048) 32x64 swizzled
// prologue overlays: OBS [8192,16384) 32x256 ; BS/hobs [16384,20480) 32x128
#define W2S_OFF  0
#define HS_OFF   8192
#define H2S_OFF  16384
#define OBS_OFF  8192
#define BS_OFF   16384
#define LDS_FLOATS 20480     // 81920 B -> exactly 2 blocks/CU (160 KiB pool)

// row-dependent XOR swizzles (float-unit offsets, 4-aligned -> b128-safe)
#define X1(r) (((r) & 7) << 2)   // Hs  (row stride 128)
#define X2(r) (((r) & 7) << 3)   // H2s (row stride 64)

// ---------------------------------------------------------------------------
// 512 threads = 2 teams x 256. Block = 32 tokens, grid 512.
// Structure validated R10 (passed, absmax 4.8e-7); R10 regression was VGPR=64
// spill from launch_bounds(512,4) leaving max-occupancy unpinned. Fix:
// amdgpu_waves_per_eu(4,4) pins min=max -> full 128-VGPR budget, no spill.
// ---------------------------------------------------------------------------
__global__ void
__attribute__((amdgpu_flat_work_group_size(512, 512)))
__attribute__((amdgpu_waves_per_eu(4, 4)))
k_fused(
    const float* __restrict__ obs, const float* __restrict__ actions,
    const float* __restrict__ cf, const float* __restrict__ W1,
    const float* __restrict__ b1, const float* __restrict__ W2,
    const float* __restrict__ b2v, const float* __restrict__ W3,
    const float* __restrict__ b3v, float* __restrict__ out)
{
    __shared__ float lds[LDS_FLOATS];

    const int tid  = threadIdx.x;
    const int team = tid >> 8;
    const int ttid = tid & 255;
    const int g0   = blockIdx.x * 32;

    // prologue mapping: 2 tok x 4 col over 512 threads
    const int rp = tid >> 5;            // 0..15 -> rows rp*2+{0,1}
    const int cp = tid & 31;            // cols cp*4
    // team mappings (on ttid, identical to validated R6 kernel)
    const int rb1 = ttid >> 5, cb1 = ttid & 31;       // GEMM1: 4 tok x 4 col
    const int kh  = ttid >> 7;                        // GEMM2 k-half
    const int rg  = (ttid >> 4) & 7, cg = ttid & 15;  // GEMM2: 4 tok x 4 col
    const int r3  = ttid >> 3, cb3 = ttid & 7;        // GEMM3: 1 tok x 4 col

    // ---- stage W2 (shared, 2048 f4) + obs tile (2048 f4) ----
    #pragma unroll
    for (int j = 0; j < 4; ++j) {
        int idx = tid + j * 512;
        *(f4*)(lds + W2S_OFF + idx * 4) = *(const f4*)(W2 + idx * 4);
        *(f4*)(lds + OBS_OFF + idx * 4) = *(const f4*)(obs + g0 * OBSD + idx * 4);
    }
    __syncthreads();

    // ---- prologue obs-GEMM: K=256 in 8 staged k-tiles ----
    f4 pacc[2] = {{0.f,0.f,0.f,0.f},{0.f,0.f,0.f,0.f}};
    for (int kt = 0; kt < OBSD; kt += 32) {
        // stage W1 rows kt..kt+31 (1024 f4)
        #pragma unroll
        for (int j = 0; j < 2; ++j) {
            int idx = tid + j * 512;
            *(f4*)(lds + BS_OFF + idx * 4) = *(const f4*)(W1 + kt * H1D + idx * 4);
        }
        __syncthreads();
        #pragma unroll
        for (int k0 = 0; k0 < 32; k0 += 4) {
            f4 a0 = *(const f4*)(lds + OBS_OFF + (rp * 2 + 0) * OBSD + kt + k0);
            f4 a1 = *(const f4*)(lds + OBS_OFF + (rp * 2 + 1) * OBSD + kt + k0);
            #pragma unroll
            for (int kk = 0; kk < 4; ++kk) {
                f4 b = *(const f4*)(lds + BS_OFF + (k0 + kk) * H1D + cp * 4);
                pacc[0] += b * a0[kk];
                pacc[1] += b * a1[kk];
            }
        }
        __syncthreads();
    }
    // write hobs (+b1) to handoff buffer (BS region dead)
    {
        f4 bias = *(const f4*)(b1 + cp * 4);
        *(f4*)(lds + BS_OFF + (rp * 2 + 0) * H1D + cp * 4) = pacc[0] + bias;
        *(f4*)(lds + BS_OFF + (rp * 2 + 1) * H1D + cp * 4) = pacc[1] + bias;
    }
    __syncthreads();
    // each team-thread reads its 4x4 hobs fragment
    f4 hobs[4];
    #pragma unroll
    for (int i = 0; i < 4; ++i)
        hobs[i] = *(const f4*)(lds + BS_OFF + (rb1 * 4 + i) * H1D + cb1 * 4);
    __syncthreads();   // handoff region becomes H2s

    const float* W1a = W1 + OBSD * H1D;
    f4 bias2 = *(const f4*)(b2v + cg * 4);
    f4 bias3 = *(const f4*)(b3v + cb3 * 4);

    // eval-invariant GEMM1-A addressing (validated in R6)
    const int row0 = rb1 * 4;
    const float* act_src = actions + (g0 + row0) * ACTD;
    const float* cf_base = cf + (row0 & 15) * (SCF * BT * ACTD)
                              + ((g0 >> 4) + (row0 >> 4)) * ACTD;

    const int hsT  = HS_OFF  + team * 4096;
    const int h2sT = H2S_OFF + team * 2048;

    f4 pw = {0.f, 0.f, 0.f, 0.f};
    f4 pq = {0.f, 0.f, 0.f, 0.f};

    // ================= team eval loop: 9 evals each =================
    for (int ee = 0; ee < 9; ++ee) {
        const bool zeroEval = (team == 1) && (ee == 0);
        const bool withEval = (team == 0) && (ee == 0);

        // --- GEMM1: h1 = relu(hobs + act @ W1a); A,B via global/L1 ---
        f4 hv[4];
        if (!zeroEval) {
            const float* asrc;
            int astr;
            if (withEval) { asrc = act_src; astr = ACTD; }
            else {
                int s = ee - 1 + team * 8;
                asrc = cf_base + s * (BT * ACTD);
                astr = SCF * BT * ACTD;
            }
            f4 a1c[4] = {{0.f,0.f,0.f,0.f},{0.f,0.f,0.f,0.f},
                         {0.f,0.f,0.f,0.f},{0.f,0.f,0.f,0.f}};
            #pragma unroll
            for (int k0 = 0; k0 < ACTD; k0 += 4) {
                f4 a[4];
                #pragma unroll
                for (int i = 0; i < 4; ++i)
                    a[i] = *(const f4*)(asrc + i * astr + k0);
                #pragma unroll
                for (int kk = 0; kk < 4; ++kk) {
                    f4 b = *(const f4*)(W1a + (k0 + kk) * H1D + cb1 * 4);
                    #pragma unroll
                    for (int i = 0; i < 4; ++i)
                        a1c[i] += b * a[i][kk];
                }
            }
            #pragma unroll
            for (int i = 0; i < 4; ++i)
                #pragma unroll
                for (int j = 0; j < 4; ++j)
                    hv[i][j] = fmaxf(hobs[i][j] + a1c[i][j], 0.f);
        } else {
            #pragma unroll
            for (int i = 0; i < 4; ++i)
                #pragma unroll
                for (int j = 0; j < 4; ++j)
                    hv[i][j] = fmaxf(hobs[i][j], 0.f);
        }
        #pragma unroll
        for (int i = 0; i < 4; ++i) {
            int r = rb1 * 4 + i;
            *(f4*)(lds + hsT + r * H1D + ((cb1 * 4) ^ X1(r))) = hv[i];
        }
        __syncthreads();  // B_a: team Hs visible

        // --- GEMM2 split-k on shared W2s ---
        f4 acc2[4] = {{0.f,0.f,0.f,0.f},{0.f,0.f,0.f,0.f},
                      {0.f,0.f,0.f,0.f},{0.f,0.f,0.f,0.f}};
        {
            const int kb = kh * 64;
            #pragma unroll 8
            for (int k0 = 0; k0 < 64; k0 += 4) {
                f4 a[4];
                #pragma unroll
                for (int i = 0; i < 4; ++i) {
                    int r = rg * 4 + i;
                    a[i] = *(const f4*)(lds + hsT + r * H1D + ((kb + k0) ^ X1(r)));
                }
                #pragma unroll
                for (int kk = 0; kk < 4; ++kk) {
                    f4 b = *(const f4*)(lds + W2S_OFF + (kb + k0 + kk) * H2D + cg * 4);
                    #pragma unroll
                    for (int i = 0; i < 4; ++i)
                        acc2[i] += b * a[i][kk];
                }
            }
        }
        if (kh) {
            #pragma unroll
            for (int i = 0; i < 4; ++i) {
                int r = rg * 4 + i;
                *(f4*)(lds + h2sT + r * H2D + ((cg * 4) ^ X2(r))) = acc2[i];
            }
        }
        __syncthreads();  // B_b: partials visible
        if (!kh) {
            #pragma unroll
            for (int i = 0; i < 4; ++i) {
                int r = rg * 4 + i;
                float* p = lds + h2sT + r * H2D + ((cg * 4) ^ X2(r));
                f4 part = *(const f4*)p;
                f4 v;
                #pragma unroll
                for (int j = 0; j < 4; ++j)
                    v[j] = fmaxf(acc2[i][j] + part[j] + bias2[j], 0.f);
                *(f4*)p = v;
            }
        }
        __syncthreads();  // B_c: team H2s final

        // --- GEMM3: p = h2 @ W3 + b3 (W3 via L1) ---
        {
            f4 a3 = {0.f, 0.f, 0.f, 0.f};
            #pragma unroll 8
            for (int k0 = 0; k0 < H2D; k0 += 4) {
                f4 a = *(const f4*)(lds + h2sT + r3 * H2D + (k0 ^ X2(r3)));
                #pragma unroll
                for (int kk = 0; kk < 4; ++kk) {
                    f4 b = *(const f4*)(W3 + (k0 + kk) * ACTD + cb3 * 4);
                    a3 += b * a[kk];
                }
            }
            a3 += bias3;
            if (withEval) pw = a3;
            else {
                pq += a3;   // includes team1's zero eval
            }
        }
        __syncthreads();  // B_d: GEMM3 reads done before next eval's writes
    }

    // ================= combine + KL (team0) =================
    if (team) {
        // publish team1 pq into team1's dead Hs region
        *(f4*)(lds + HS_OFF + 4096 + r3 * 32 + cb3 * 4) = pq;
    }
    __syncthreads();
    if (!team) {
        f4 pq1 = *(const f4*)(lds + HS_OFF + 4096 + r3 * 32 + cb3 * 4);
        const float inv17 = 1.0f / 17.0f;
        f4 qv;
        #pragma unroll
        for (int j = 0; j < 4; ++j) qv[j] = (pq[j] + pq1[j]) * inv17;

        float mw = fmaxf(fmaxf(pw[0], pw[1]), fmaxf(pw[2], pw[3]));
        float mq = fmaxf(fmaxf(qv[0], qv[1]), fmaxf(qv[2], qv[3]));
        #pragma unroll
        for (int m = 1; m < 8; m <<= 1) {
            mw = fmaxf(mw, __shfl_xor(mw, m));
            mq = fmaxf(mq, __shfl_xor(mq, m));
        }
        float sw = 0.f, sq = 0.f;
        #pragma unroll
        for (int j = 0; j < 4; ++j) {
            sw += expf(pw[j] - mw);
            sq += expf(qv[j] - mq);
        }
        #pragma unroll
        for (int m = 1; m < 8; m <<= 1) {
            sw += __shfl_xor(sw, m);
            sq += __shfl_xor(sq, m);
        }
        const float lsw = logf(sw), lsq = logf(sq);
        float kl = 0.f;
        #pragma unroll
        for (int j = 0; j < 4; ++j) {
            float lq = qv[j] - mq - lsq;
            float lp = pw[j] - mw - lsw;
            kl += expf(lq) * (lq - lp);
        }
        #pragma unroll
        for (int m = 1; m < 8; m <<= 1) kl += __shfl_xor(kl, m);

        if (cb3 == 0) out[g0 + r3] = kl * (1.0f / 32.0f);
    }
}

// ---------------------------------------------------------------------------
extern "C" void kernel_launch(void* const* d_in, const int* in_sizes, int n_in,
                              void* d_out, int out_size, void* d_ws, size_t ws_size,
                              hipStream_t stream)
{
    const float* obs     = (const float*)d_in[0];
    const float* actions = (const float*)d_in[1];
    const float* cf      = (const float*)d_in[2];
    const float* W1      = (const float*)d_in[3];
    const float* b1      = (const float*)d_in[4];
    const float* W2      = (const float*)d_in[5];
    const float* b2      = (const float*)d_in[6];
    const float* W3      = (const float*)d_in[7];
    const float* b3      = (const float*)d_in[8];
    float* outp = (float*)d_out;

    k_fused<<<NTOK / 32, 512, 0, stream>>>(obs, actions, cf, W1, b1, W2,
                                           b2, W3, b3, outp);
}